// Round 4
// baseline (715.694 us; speedup 1.0000x reference)
//
#include <hip/hip_runtime.h>
#include <math.h>

// LocalAggregationLoss, R5: bucketed gather (locality attack).
//   R1/R2/R4 (three different MLP structures) all tie at ~590us -> the wall
//   is the random-512B access PATTERN (~0.8 TB/s effective), not issue
//   parallelism. This round keeps request count identical but makes the
//   pattern local: references bucketed by row>>8 (128KB bank windows),
//   one block per bucket gathers only referenced rows -> DRAM page/TLB
//   locality + dup rows become L2 hits.
// Pipeline (4 launches, ~3.6MB of d_ws):
//   k_prep   : zero cnt/dacc + vtab[b] = normalize(codes[b])
//   k_scatter: rec=(row<<11|list<<10|b) -> recs[buk*192 + atomicAdd(cnt[buk])]
//              (overflow >192/bucket: ~P=1e-13, handled inline for correctness)
//   k_main   : 3907 blocks; block g processes bucket g's entries: row load
//              (local 128KB window), dot vs vtab[b] (L2-hot), exp,
//              atomicAdd dacc[list*B+b]  (burst x4 per 32-lane group)
//   k_fin    : out[b] = log(d1)-log(d2)
// Decision rule: ~430-480us => locality was the wall; ~595+ => per-request
// wall confirmed, scattered-gather roofline.

constexpr int   DIM   = 128;
constexpr int   KN    = 200;
constexpr int   NBANK = 1000000;
constexpr int   NBUK  = (NBANK + 255) / 256;   // 3907 buckets of 256 rows
constexpr int   MAXPB = 192;                   // slab slots per bucket
constexpr float INV_T = 1.0f / 0.07f;

// ---------------- R5 kernels ----------------

__global__ __launch_bounds__(128)
void k_prep(const float* __restrict__ codes, float* __restrict__ vtab,
            int* __restrict__ cnt, float* __restrict__ dacc, int batch)
{
    const int b = blockIdx.x;
    const int t = threadIdx.x;

    // zero cnt[NBUK] and dacc[2*batch] (grid covers 1024*128 threads)
    const int gt = b * 128 + t;
    if (gt < NBUK) cnt[gt] = 0;
    else if (gt < NBUK + 2 * batch) dacc[gt - NBUK] = 0.0f;

    // vtab[b] = normalize(codes[b])
    __shared__ float w[2];
    float c  = codes[b * DIM + t];
    float ss = c * c;
    #pragma unroll
    for (int m = 32; m > 0; m >>= 1) ss += __shfl_xor(ss, m, 64);
    if ((t & 63) == 0) w[t >> 6] = ss;
    __syncthreads();
    const float rn = 1.0f / sqrtf(w[0] + w[1]);
    vtab[b * DIM + t] = c * rn;
}

__global__ __launch_bounds__(256)
void k_scatter(const int* __restrict__ idx_bg, const int* __restrict__ idx_cl,
               const float* __restrict__ bank, const float* __restrict__ vtab,
               unsigned int* __restrict__ recs, int* __restrict__ cnt,
               float* __restrict__ dacc, int batch)
{
    const int bk = batch * KN;
    const int n  = 2 * bk;
    for (int e = blockIdx.x * blockDim.x + threadIdx.x; e < n;
         e += gridDim.x * blockDim.x) {
        const int list = (e >= bk) ? 1 : 0;
        const int off  = e - list * bk;
        const int row  = (list ? idx_cl : idx_bg)[off];
        const int b    = off / KN;
        const unsigned int rec = ((unsigned int)row << 11)
                               | ((unsigned int)list << 10)
                               | (unsigned int)b;
        const int buk = row >> 8;
        const int pos = atomicAdd(&cnt[buk], 1);
        if (pos < MAXPB) {
            recs[buk * MAXPB + pos] = rec;
        } else {
            // statistically-never overflow: accumulate directly (correctness)
            const float4* br = (const float4*)(bank + (size_t)row * DIM);
            const float4* vr = (const float4*)(vtab + (size_t)b * DIM);
            float d = 0.0f;
            for (int i = 0; i < DIM / 4; ++i) {
                float4 x = br[i], v = vr[i];
                d += x.x * v.x + x.y * v.y + x.z * v.z + x.w * v.w;
            }
            atomicAdd(&dacc[list * batch + b], __expf(d * INV_T));
        }
    }
}

__global__ __launch_bounds__(256)
void k_main(const float* __restrict__ bank, const unsigned int* __restrict__ recs,
            const int* __restrict__ cnt, const float* __restrict__ vtab,
            float* __restrict__ dacc, int batch)
{
    const int g   = blockIdx.x;
    const int tid = threadIdx.x;

    __shared__ unsigned int s_recs[MAXPB];
    const int n = min(cnt[g], MAXPB);
    for (int i = tid; i < n; i += 256) s_recs[i] = recs[g * MAXPB + i];
    __syncthreads();
    if (n == 0) return;

    const int group = tid >> 5;   // 8 groups
    const int lane  = tid & 31;   // 32 lanes x 16B = one 512B row

    // burst x4 per group: 8 independent loads (4 bank rows in this bucket's
    // 128KB window + 4 L2-hot vtab rows) in flight before the reduce chain.
    for (int base = group * 4; base < n; base += 32) {
        const int m = min(4, n - base);
        float4 x[4], w[4];
        int    di[4];
        #pragma unroll
        for (int u = 0; u < 4; ++u) {
            if (u < m) {
                const unsigned int rec = s_recs[base + u];
                const int b    = rec & 1023;
                const int list = (rec >> 10) & 1;
                const int row  = rec >> 11;
                x[u]  = ((const float4*)(bank + (size_t)row * DIM))[lane];
                w[u]  = ((const float4*)(vtab + (size_t)b * DIM))[lane];
                di[u] = list * batch + b;
            }
        }
        #pragma unroll
        for (int u = 0; u < 4; ++u) {
            if (u < m) {
                float d = x[u].x * w[u].x + x[u].y * w[u].y
                        + x[u].z * w[u].z + x[u].w * w[u].w;
                d += __shfl_xor(d, 16, 32);
                d += __shfl_xor(d, 8, 32);
                d += __shfl_xor(d, 4, 32);
                d += __shfl_xor(d, 2, 32);
                d += __shfl_xor(d, 1, 32);
                if (lane == 0) atomicAdd(&dacc[di[u]], __expf(d * INV_T));
            }
        }
    }
}

__global__ __launch_bounds__(256)
void k_fin(const float* __restrict__ dacc, float* __restrict__ out, int batch)
{
    const int b = blockIdx.x * blockDim.x + threadIdx.x;
    if (b < batch) out[b] = logf(dacc[b]) - logf(dacc[batch + b]);
}

// ---------------- fallback (R1 structure, known-good) ----------------

constexpr int RPG = 25;
constexpr int UF  = 5;

__global__ __launch_bounds__(256, 4)
void lal_fallback(const float* __restrict__ codes,
                  const float* __restrict__ bank,
                  const int*   __restrict__ idx_bg,
                  const int*   __restrict__ idx_cl,
                  float*       __restrict__ out)
{
    const int b   = blockIdx.x;
    const int tid = threadIdx.x;

    __shared__ float v[DIM];
    __shared__ int   s_ib[KN];
    __shared__ int   s_ic[KN];
    __shared__ float wsum[4];
    __shared__ float red1[8];
    __shared__ float red2[8];
    __shared__ float s_rnorm;

    if (tid < KN) {
        s_ib[tid] = idx_bg[b * KN + tid];
        s_ic[tid] = idx_cl[b * KN + tid];
    }

    float c  = (tid < DIM) ? codes[b * DIM + tid] : 0.0f;
    float ss = c * c;
    #pragma unroll
    for (int m = 32; m > 0; m >>= 1) ss += __shfl_xor(ss, m, 64);
    if ((tid & 63) == 0) wsum[tid >> 6] = ss;
    __syncthreads();
    if (tid == 0) {
        float t = wsum[0] + wsum[1] + wsum[2] + wsum[3];
        s_rnorm = 1.0f / sqrtf(t);
    }
    __syncthreads();
    if (tid < DIM) v[tid] = c * s_rnorm;
    __syncthreads();

    const int group = tid >> 5;
    const int lane  = tid & 31;
    const float4 vv = ((const float4*)v)[lane];
    const int kbase = group * RPG;

    float sum1 = 0.0f, sum2 = 0.0f;

    #pragma unroll 1
    for (int j = 0; j < RPG; j += UF) {
        float4 x1[UF], x2[UF];
        #pragma unroll
        for (int u = 0; u < UF; ++u) {
            const int r1 = s_ib[kbase + j + u];
            const int r2 = s_ic[kbase + j + u];
            x1[u] = ((const float4*)(bank + (size_t)r1 * DIM))[lane];
            x2[u] = ((const float4*)(bank + (size_t)r2 * DIM))[lane];
        }
        #pragma unroll
        for (int u = 0; u < UF; ++u) {
            float d1 = x1[u].x * vv.x + x1[u].y * vv.y + x1[u].z * vv.z + x1[u].w * vv.w;
            float d2 = x2[u].x * vv.x + x2[u].y * vv.y + x2[u].z * vv.z + x2[u].w * vv.w;
            #pragma unroll
            for (int m = 16; m > 0; m >>= 1) {
                d1 += __shfl_xor(d1, m, 64);
                d2 += __shfl_xor(d2, m, 64);
            }
            sum1 += __expf(d1 * INV_T);
            sum2 += __expf(d2 * INV_T);
        }
    }

    if (lane == 0) { red1[group] = sum1; red2[group] = sum2; }
    __syncthreads();
    if (tid == 0) {
        float D1 = 0.0f, D2 = 0.0f;
        #pragma unroll
        for (int g = 0; g < 8; ++g) { D1 += red1[g]; D2 += red2[g]; }
        out[b] = logf(D1) - logf(D2);
    }
}

// ---------------- launcher ----------------

extern "C" void kernel_launch(void* const* d_in, const int* in_sizes, int n_in,
                              void* d_out, int out_size, void* d_ws, size_t ws_size,
                              hipStream_t stream)
{
    const float* codes  = (const float*)d_in[0];
    const float* bank   = (const float*)d_in[1];
    const int*   idx_bg = (const int*)d_in[2];
    const int*   idx_cl = (const int*)d_in[3];
    float*       out    = (float*)d_out;

    const int batch = in_sizes[0] / DIM;   // 1024

    if (batch == 1024 && ws_size >= (size_t)(8u << 20)) {
        // ws layout: vtab 512KB | dacc 8KB | cnt 16KB | recs ~3MB
        char*         ws   = (char*)d_ws;
        float*        vtab = (float*)(ws);
        float*        dacc = (float*)(ws + 524288);
        int*          cnt  = (int*)  (ws + 524288 + 8192);
        unsigned int* recs = (unsigned int*)(ws + 524288 + 8192 + 16384);

        const int n = 2 * batch * KN;
        k_prep   <<<batch, 128, 0, stream>>>(codes, vtab, cnt, dacc, batch);
        k_scatter<<<(n + 255) / 256, 256, 0, stream>>>(idx_bg, idx_cl, bank,
                                                       vtab, recs, cnt, dacc, batch);
        k_main   <<<NBUK, 256, 0, stream>>>(bank, recs, cnt, vtab, dacc, batch);
        k_fin    <<<(batch + 255) / 256, 256, 0, stream>>>(dacc, out, batch);
    } else {
        lal_fallback<<<batch, 256, 0, stream>>>(codes, bank, idx_bg, idx_cl, out);
    }
}